// Round 2
// baseline (510.745 us; speedup 1.0000x reference)
//
#include <hip/hip_runtime.h>

// ============================================================================
// SE3 two-layer point kernel, MI355X (gfx950)
// Output: (36,36,256,256) fp32, ~340 MB -> HBM-write floor ~54-85us.
//
// R2 change: defeat REMATERIALIZATION.
//   R1 evidence: VGPR_Count=64 despite launch_bounds allowing 256, zero scratch
//   traffic, and ~8x dynamic VALU instructions vs static FMA count (1.67e8 vs
//   2.1e7 wave-instr). Conclusion: LLVM's remat cost model recomputes the
//   Y[] spherical-harmonic chains and c[][] radial-collapse chains at every
//   use inside the 25-iteration (a,b) loop instead of keeping them resident.
//   Fix: pin each precomputed value with asm volatile("" : "+v"(x)) -- the def
//   becomes opaque volatile asm, which cannot be rematerialized or sunk, so
//   values must stay in VGPRs (launch_bounds(256,2) allows up to 256).
//   Numerics bit-identical.
// ============================================================================

#define DEV __device__ __forceinline__
#define PIN(x) asm volatile("" : "+v"(x))

// ----- compile-time path metadata: path p = lo*3 + li ------------------------
constexpr int PW0[9]   = {0,40,80,120,160,280,400,440,560};   // weight_0 offsets
constexpr int PQOFF[9] = {0,1,10,35,44,125,350,375,600};      // Q table base (floats)
constexpr int YBASE[5] = {0,1,4,9,16};                        // Y row offset per J

__host__ __device__ constexpr int qlocal(int DO, int DI, int JS, int j) {
  int o = 0;
  for (int k = 0; k < j; ++k) o += DO * DI * (2 * (JS + k) + 1);
  return o;
}

// ============================================================================
// Init kernel: build the 19 Q tables (fp64) into ws[0..1225)
// ============================================================================
__device__ double dfact(int n) { double f = 1.0; for (int i = 2; i <= n; ++i) f *= (double)i; return f; }

__device__ double cgc(int l1, int m1, int l2, int m2, int l3, int m3) {
  if (m1 + m2 != m3) return 0.0;
  double pre = sqrt((2.0 * l3 + 1.0) * dfact(l3 + l1 - l2) * dfact(l3 - l1 + l2) *
                    dfact(l1 + l2 - l3) / dfact(l1 + l2 + l3 + 1));
  pre *= sqrt(dfact(l3 + m3) * dfact(l3 - m3) * dfact(l1 - m1) * dfact(l1 + m1) *
              dfact(l2 - m2) * dfact(l2 + m2));
  double s = 0.0;
  for (int k = 0; k <= l1 + l2 - l3; ++k) {
    int d1 = l1 + l2 - l3 - k, d2 = l1 - m1 - k, d3 = l2 + m2 - k;
    int d4 = l3 - l2 + m1 + k, d5 = l3 - l1 - m2 + k;
    if (d1 < 0 || d2 < 0 || d3 < 0 || d4 < 0 || d5 < 0) continue;
    double term = 1.0 / (dfact(k) * dfact(d1) * dfact(d2) * dfact(d3) * dfact(d4) * dfact(d5));
    s += (k & 1) ? -term : term;
  }
  return pre * s;
}

// nonzero entries of real-basis transform U(l) row a (complex); returns count
__device__ int urow(int l, int a, int* col, double* re, double* im) {
  const double RS = 0.7071067811865476;
  int m = a - l;
  if (m == 0) { col[0] = l; re[0] = 1.0; im[0] = 0.0; return 1; }
  if (m > 0) {
    double s = (m & 1) ? -1.0 : 1.0;
    col[0] = l + m; re[0] = s * RS; im[0] = 0.0;
    col[1] = l - m; re[1] = RS;     im[1] = 0.0;
    return 2;
  }
  int mm = -m;
  double s = (mm & 1) ? -1.0 : 1.0;
  col[0] = l + mm; re[0] = 0.0; im[0] = -s * RS;
  col[1] = l - mm; re[1] = 0.0; im[1] = RS;
  return 2;
}

__global__ __launch_bounds__(256) void init_q_kernel(float* __restrict__ ws) {
  constexpr int T_LO[19]  = {0,0,0, 1, 1,1,1, 1,1,1, 2, 2,2,2, 2,2,2,2,2};
  constexpr int T_LI[19]  = {0,1,2, 0, 1,1,1, 2,2,2, 0, 1,1,1, 2,2,2,2,2};
  constexpr int T_J [19]  = {0,1,2, 1, 0,1,2, 1,2,3, 2, 1,2,3, 0,1,2,3,4};
  constexpr int T_OFF[19] = {0,1,10,35,44,53,80,125,170,245,350,375,420,495,600,625,700,825,1000};

  const int t  = blockIdx.x;
  const int lo = T_LO[t], li = T_LI[t], J = T_J[t];
  const int d_o = 2 * lo + 1, d_i = 2 * li + 1, w = 2 * J + 1;
  const int size = d_o * d_i * w;
  const int e = threadIdx.x;

  double tre = 0.0, tim = 0.0;
  if (e < size) {
    int row = e / w, cc = e % w;
    int a = row / d_i, b = row % d_i;
    int co[2], ci[2], cj[2];
    double ro[2], io[2], ri[2], ii[2], rj[2], ij[2];
    int no = urow(lo, a,  co, ro, io);
    int ni = urow(li, b,  ci, ri, ii);
    int nj = urow(J,  cc, cj, rj, ij);
    // T[a,b,cc] = sum Uo[a,p] * conj(Ui[b,q]) * conj(UJ[cc,r]) * CG(li,q-li, J,r-J, lo,p-lo)
    for (int i0 = 0; i0 < no; ++i0)
      for (int i1 = 0; i1 < ni; ++i1)
        for (int i2 = 0; i2 < nj; ++i2) {
          double cg = cgc(li, ci[i1] - li, J, cj[i2] - J, lo, co[i0] - lo);
          if (cg == 0.0) continue;
          double ar = ro[i0], ai = io[i0];
          double br = ri[i1], bi = -ii[i1];   // conj
          double cr = rj[i2], cii = -ij[i2];  // conj
          double abr = ar * br - ai * bi, abi = ar * bi + ai * br;
          double pr = abr * cr - abi * cii, pi = abr * cii + abi * cr;
          tre += pr * cg; tim += pi * cg;
        }
  }
  // per-table choice: real part if sum|Re| >= sum|Im| (matches reference)
  __shared__ double sre[256], sim[256];
  sre[threadIdx.x] = fabs(tre);
  sim[threadIdx.x] = fabs(tim);
  __syncthreads();
  for (int s = 128; s > 0; s >>= 1) {
    if (threadIdx.x < s) { sre[threadIdx.x] += sre[threadIdx.x + s]; sim[threadIdx.x] += sim[threadIdx.x + s]; }
    __syncthreads();
  }
  if (e < size) ws[T_OFF[t] + e] = (float)((sre[0] >= sim[0]) ? tre : tim);
}

// ============================================================================
// Main kernel
// ============================================================================
template <int P>
DEV void do_path(const float* __restrict__ diff,
                 const float* __restrict__ w0g, const float* __restrict__ b0g,
                 const float* __restrict__ w1g, const float* __restrict__ b1g,
                 const float* __restrict__ Q, float* __restrict__ out,
                 int n, int m) {
  constexpr int LO = P / 3, LI = P % 3;
  constexpr int DO = 2 * LO + 1, DI = 2 * LI + 1;
  constexpr int JS = (LO > LI) ? (LO - LI) : (LI - LO);   // J start
  constexpr int NJ = 2 * ((LO < LI) ? LO : LI) + 1;        // number of J's
  constexpr int BEL = 4 * NJ;                              // b_el = radii * nJ
  constexpr int ROFF = (LO == 0) ? 0 : ((LO == 1) ? 4 : 16);
  constexpr int COFF = (LI == 0) ? 0 : ((LI == 1) ? 4 : 16);
  constexpr int W0OFF = PW0[P];
  constexpr int QOFF  = PQOFF[P];
  constexpr int YTOP  = (LO + LI + 1) * (LO + LI + 1);     // Y entries actually used
  const float FV0 = sqrtf((float)DO / (10.0f * (float)BEL * 9.0f));
  const float FV1 = sqrtf((float)DO / 360.0f);

  const float* dp = diff + (((size_t)n << 8) + (size_t)m) * 3;
  const float dx = dp[0], dy = dp[1], dz = dp[2];
  const float r2 = dx * dx + dy * dy + dz * dz;
  const float r  = sqrtf(r2);
  const float rr = fmaxf(r, 1e-8f);
  const float inv = 1.0f / rr;
  const float x = dx * inv, y = dy * inv, z = dz * inv;

  // Gaussian windows, pre-scaled by fv0 (folds layer-0 scale)
  float wv[4];
  {
    const float NORMC = 0.6649038006690546f;  // 1/(0.6*sqrt(2pi))
    const float RAD[4] = {0.5f, 1.0f, 1.5f, 2.0f};
#pragma unroll
    for (int k = 0; k < 4; ++k) {
      float tq = (r - RAD[k]) * (1.0f / 0.6f);
      wv[k] = expf(-0.5f * tq * tq) * (NORMC * FV0);
    }
  }

  // real spherical harmonics, replicating reference recurrences EXACTLY.
  // NOTE: reference appends A before computing B, so B[m] uses the NEW A[m].
  float Y[25];
  {
    const float A1 = x,                 B1 = y * A1;
    const float A2 = x * A1 - y * B1,   B2 = x * B1 + y * A2;
    const float A3 = x * A2 - y * B2,   B3 = x * B2 + y * A3;
    const float A4 = x * A3 - y * B3,   B4 = x * B3 + y * A4;
    const float z2 = z * z;
    Y[0]  = 0.28209479177387814f;
    Y[1]  = 0.4886025119029199f * B1;
    Y[2]  = 0.4886025119029199f * z;
    Y[3]  = 0.4886025119029199f * A1;
    Y[4]  = 0.5462742152960396f * B2;
    Y[5]  = 1.0925484305920792f * z * B1;
    Y[6]  = 0.31539156525252005f * (3.0f * z2 - 1.0f);
    Y[7]  = 1.0925484305920792f * z * A1;
    Y[8]  = 0.5462742152960396f * A2;
    Y[9]  = 0.5900435899266435f * B3;
    Y[10] = 1.445305721320277f * z * B2;
    Y[11] = 0.4570457994644658f * (5.0f * z2 - 1.0f) * B1;
    Y[12] = 0.3731763325901154f * z * (5.0f * z2 - 3.0f);
    Y[13] = 0.4570457994644658f * (5.0f * z2 - 1.0f) * A1;
    Y[14] = 1.445305721320277f * z * A2;
    Y[15] = 0.5900435899266435f * A3;
    Y[16] = 0.6258357354491761f * B4;
    Y[17] = 1.7701307697799304f * z * B3;
    Y[18] = 0.47308734787878004f * (7.0f * z2 - 1.0f) * B2;
    Y[19] = 0.6690465435572892f * z * (7.0f * z2 - 3.0f) * B1;
    Y[20] = 0.10578554691520431f * ((35.0f * z2 - 30.0f) * z2 + 3.0f);
    Y[21] = 0.6690465435572892f * z * (7.0f * z2 - 3.0f) * A1;
    Y[22] = 0.47308734787878004f * (7.0f * z2 - 1.0f) * A2;
    Y[23] = 1.7701307697799304f * z * A3;
    Y[24] = 0.6258357354491761f * A4;
  }
  // Pin every Y this path uses: def becomes opaque volatile asm -> cannot be
  // rematerialized inside the (a,b) loop; must stay resident in a VGPR.
#pragma unroll
  for (int i = 0; i < YTOP; ++i) PIN(Y[i]);

  // collapse radial dim: c[t][j] = sum_r w0[t, r*NJ+j] * win_r * fv0
  float c[10][NJ];
#pragma unroll
  for (int t = 0; t < 10; ++t) {
#pragma unroll
    for (int j = 0; j < NJ; ++j) {
      float acc = 0.0f;
#pragma unroll
      for (int rx = 0; rx < 4; ++rx)
        acc = fmaf(w0g[W0OFF + t * BEL + rx * NJ + j], wv[rx], acc);
      PIN(acc);
      c[t][j] = acc;
    }
  }
  float b0v[10];
#pragma unroll
  for (int t = 0; t < 10; ++t) b0v[t] = b0g[10 * P + t];

  // uniform base for this block's n-row; per-lane offset is just m
  float* __restrict__ outn = out + ((size_t)n << 8);
  const float* __restrict__ w1p = w1g + 160 * P;
  const float* __restrict__ b1p = b1g + 16 * P;

#pragma unroll 1
  for (int a = 0; a < DO; ++a) {
#pragma unroll 1
    for (int b = 0; b < DI; ++b) {
      // K[j] = sum_c Q[(a*DI+b), c] * Y_J[c]
      float K[NJ];
#pragma unroll
      for (int j = 0; j < NJ; ++j) {
        const int W = 2 * (JS + j) + 1;
        const int qbase = QOFF + qlocal(DO, DI, JS, j) + (a * DI + b) * W;
        float acc = 0.0f;
#pragma unroll
        for (int cc = 0; cc < 2 * (JS + j) + 1; ++cc)
          acc = fmaf(Q[qbase + cc], Y[YBASE[JS + j] + cc], acc);
        K[j] = acc;
      }
      // layer 0
      float h[10];
#pragma unroll
      for (int t = 0; t < 10; ++t) {
        float acc = b0v[t];
#pragma unroll
        for (int j = 0; j < NJ; ++j) acc = fmaf(c[t][j], K[j], acc);
        h[t] = fmaxf(acc, 0.0f);
      }
      // layer 1 + scatter (coalesced along m); plane pointer is wave-uniform
#pragma unroll
      for (int u = 0; u < 4; ++u) {
        const int Rr = ROFF + u * DO + a;
#pragma unroll
        for (int v = 0; v < 4; ++v) {
          const int uv = u * 4 + v;
          float acc = 0.0f;
#pragma unroll
          for (int t = 0; t < 10; ++t)
            acc = fmaf(w1p[uv * 10 + t], h[t], acc);
          const float val = fmaf(acc, FV1, b1p[uv]);
          const int Cc = COFF + v * DI + b;
          float* __restrict__ op = outn + (((size_t)(Rr * 36 + Cc)) << 16);
          op[m] = val;
        }
      }
    }
  }
}

__global__ __launch_bounds__(256, 2) void se3_main_kernel(
    const float* __restrict__ diff, const float* __restrict__ w0,
    const float* __restrict__ b0, const float* __restrict__ w1,
    const float* __restrict__ b1, const float* __restrict__ Q,
    float* __restrict__ out) {
  // interleave paths across early blocks for load balance
  const int path = blockIdx.x % 9;
  const int n    = blockIdx.x / 9;
  const int m    = threadIdx.x;
  switch (path) {
    case 0: do_path<0>(diff, w0, b0, w1, b1, Q, out, n, m); break;
    case 1: do_path<1>(diff, w0, b0, w1, b1, Q, out, n, m); break;
    case 2: do_path<2>(diff, w0, b0, w1, b1, Q, out, n, m); break;
    case 3: do_path<3>(diff, w0, b0, w1, b1, Q, out, n, m); break;
    case 4: do_path<4>(diff, w0, b0, w1, b1, Q, out, n, m); break;
    case 5: do_path<5>(diff, w0, b0, w1, b1, Q, out, n, m); break;
    case 6: do_path<6>(diff, w0, b0, w1, b1, Q, out, n, m); break;
    case 7: do_path<7>(diff, w0, b0, w1, b1, Q, out, n, m); break;
    case 8: do_path<8>(diff, w0, b0, w1, b1, Q, out, n, m); break;
  }
}

extern "C" void kernel_launch(void* const* d_in, const int* in_sizes, int n_in,
                              void* d_out, int out_size, void* d_ws, size_t ws_size,
                              hipStream_t stream) {
  const float* diff = (const float*)d_in[0];
  const float* w0   = (const float*)d_in[1];
  const float* b0   = (const float*)d_in[2];
  const float* w1   = (const float*)d_in[3];
  const float* b1   = (const float*)d_in[4];
  float* out = (float*)d_out;
  float* qws = (float*)d_ws;  // needs 1225 floats; rebuilt every call (ws is re-poisoned)

  init_q_kernel<<<dim3(19), dim3(256), 0, stream>>>(qws);
  se3_main_kernel<<<dim3(256 * 9), dim3(256), 0, stream>>>(diff, w0, b0, w1, b1, qws, out);
}

// Round 3
// 439.588 us; speedup vs baseline: 1.1619x; 1.1619x over previous
//
#include <hip/hip_runtime.h>

// ============================================================================
// SE3 two-layer point kernel, MI355X (gfx950)
// Output: (36,36,256,256) fp32, ~340 MB -> HBM-write floor ~54us.
//
// R3 change: SPLIT THE 9-PATH SWITCH MEGA-KERNEL INTO PER-PATH KERNELS.
//   Evidence trail: VGPR_Count pinned at 64 across launch_bounds(256),
//   (256,2), and even with 75+ values force-pinned live via asm (R2) -- with
//   zero scratch traffic and ~8x dynamic VALU vs static FMA count. Conclusion:
//   the shared register allocation across the 9-way switch (single kernel)
//   keeps per-thread arrays out of arch VGPRs (AGPR shuffling / reload churn).
//   Fix: one kernel per heavy path (4,5,7,8) with private RA + a-dimension
//   split across blocks (3-5x more blocks for latency hiding); light paths
//   (0,1,2,3,6) bundled. Also gives per-path rocprof rows for diagnosis.
//   Per-element arithmetic is bit-identical -> absmax unchanged.
// ============================================================================

#define DEV __device__ __forceinline__

// ----- compile-time path metadata: path p = lo*3 + li ------------------------
constexpr int PW0[9]   = {0,40,80,120,160,280,400,440,560};   // weight_0 offsets
constexpr int PQOFF[9] = {0,1,10,35,44,125,350,375,600};      // Q table base (floats)
constexpr int YBASE[5] = {0,1,4,9,16};                        // Y row offset per J

__host__ __device__ constexpr int qlocal(int DO, int DI, int JS, int j) {
  int o = 0;
  for (int k = 0; k < j; ++k) o += DO * DI * (2 * (JS + k) + 1);
  return o;
}

// ============================================================================
// Init kernel: build the 19 Q tables (fp64) into ws[0..1225)
// ============================================================================
__device__ double dfact(int n) { double f = 1.0; for (int i = 2; i <= n; ++i) f *= (double)i; return f; }

__device__ double cgc(int l1, int m1, int l2, int m2, int l3, int m3) {
  if (m1 + m2 != m3) return 0.0;
  double pre = sqrt((2.0 * l3 + 1.0) * dfact(l3 + l1 - l2) * dfact(l3 - l1 + l2) *
                    dfact(l1 + l2 - l3) / dfact(l1 + l2 + l3 + 1));
  pre *= sqrt(dfact(l3 + m3) * dfact(l3 - m3) * dfact(l1 - m1) * dfact(l1 + m1) *
              dfact(l2 - m2) * dfact(l2 + m2));
  double s = 0.0;
  for (int k = 0; k <= l1 + l2 - l3; ++k) {
    int d1 = l1 + l2 - l3 - k, d2 = l1 - m1 - k, d3 = l2 + m2 - k;
    int d4 = l3 - l2 + m1 + k, d5 = l3 - l1 - m2 + k;
    if (d1 < 0 || d2 < 0 || d3 < 0 || d4 < 0 || d5 < 0) continue;
    double term = 1.0 / (dfact(k) * dfact(d1) * dfact(d2) * dfact(d3) * dfact(d4) * dfact(d5));
    s += (k & 1) ? -term : term;
  }
  return pre * s;
}

// nonzero entries of real-basis transform U(l) row a (complex); returns count
__device__ int urow(int l, int a, int* col, double* re, double* im) {
  const double RS = 0.7071067811865476;
  int m = a - l;
  if (m == 0) { col[0] = l; re[0] = 1.0; im[0] = 0.0; return 1; }
  if (m > 0) {
    double s = (m & 1) ? -1.0 : 1.0;
    col[0] = l + m; re[0] = s * RS; im[0] = 0.0;
    col[1] = l - m; re[1] = RS;     im[1] = 0.0;
    return 2;
  }
  int mm = -m;
  double s = (mm & 1) ? -1.0 : 1.0;
  col[0] = l + mm; re[0] = 0.0; im[0] = -s * RS;
  col[1] = l - mm; re[1] = 0.0; im[1] = RS;
  return 2;
}

__global__ __launch_bounds__(256) void init_q_kernel(float* __restrict__ ws) {
  constexpr int T_LO[19]  = {0,0,0, 1, 1,1,1, 1,1,1, 2, 2,2,2, 2,2,2,2,2};
  constexpr int T_LI[19]  = {0,1,2, 0, 1,1,1, 2,2,2, 0, 1,1,1, 2,2,2,2,2};
  constexpr int T_J [19]  = {0,1,2, 1, 0,1,2, 1,2,3, 2, 1,2,3, 0,1,2,3,4};
  constexpr int T_OFF[19] = {0,1,10,35,44,53,80,125,170,245,350,375,420,495,600,625,700,825,1000};

  const int t  = blockIdx.x;
  const int lo = T_LO[t], li = T_LI[t], J = T_J[t];
  const int d_o = 2 * lo + 1, d_i = 2 * li + 1, w = 2 * J + 1;
  const int size = d_o * d_i * w;
  const int e = threadIdx.x;

  double tre = 0.0, tim = 0.0;
  if (e < size) {
    int row = e / w, cc = e % w;
    int a = row / d_i, b = row % d_i;
    int co[2], ci[2], cj[2];
    double ro[2], io[2], ri[2], ii[2], rj[2], ij[2];
    int no = urow(lo, a,  co, ro, io);
    int ni = urow(li, b,  ci, ri, ii);
    int nj = urow(J,  cc, cj, rj, ij);
    for (int i0 = 0; i0 < no; ++i0)
      for (int i1 = 0; i1 < ni; ++i1)
        for (int i2 = 0; i2 < nj; ++i2) {
          double cg = cgc(li, ci[i1] - li, J, cj[i2] - J, lo, co[i0] - lo);
          if (cg == 0.0) continue;
          double ar = ro[i0], ai = io[i0];
          double br = ri[i1], bi = -ii[i1];   // conj
          double cr = rj[i2], cii = -ij[i2];  // conj
          double abr = ar * br - ai * bi, abi = ar * bi + ai * br;
          double pr = abr * cr - abi * cii, pi = abr * cii + abi * cr;
          tre += pr * cg; tim += pi * cg;
        }
  }
  // per-table choice: real part if sum|Re| >= sum|Im| (matches reference)
  __shared__ double sre[256], sim[256];
  sre[threadIdx.x] = fabs(tre);
  sim[threadIdx.x] = fabs(tim);
  __syncthreads();
  for (int s = 128; s > 0; s >>= 1) {
    if (threadIdx.x < s) { sre[threadIdx.x] += sre[threadIdx.x + s]; sim[threadIdx.x] += sim[threadIdx.x + s]; }
    __syncthreads();
  }
  if (e < size) ws[T_OFF[t] + e] = (float)((sre[0] >= sim[0]) ? tre : tim);
}

// ============================================================================
// Path body: computes rows a in [a0, a0+NA) of path P for point (n, m)
// ============================================================================
template <int P, int NA>
DEV void do_path(const float* __restrict__ diff,
                 const float* __restrict__ w0g, const float* __restrict__ b0g,
                 const float* __restrict__ w1g, const float* __restrict__ b1g,
                 const float* __restrict__ Q, float* __restrict__ out,
                 int a0, int n, int m) {
  constexpr int LO = P / 3, LI = P % 3;
  constexpr int DO = 2 * LO + 1, DI = 2 * LI + 1;
  constexpr int JS = (LO > LI) ? (LO - LI) : (LI - LO);   // J start
  constexpr int NJ = 2 * ((LO < LI) ? LO : LI) + 1;        // number of J's
  constexpr int BEL = 4 * NJ;                              // b_el = radii * nJ
  constexpr int ROFF = (LO == 0) ? 0 : ((LO == 1) ? 4 : 16);
  constexpr int COFF = (LI == 0) ? 0 : ((LI == 1) ? 4 : 16);
  constexpr int W0OFF = PW0[P];
  constexpr int QOFF  = PQOFF[P];
  const float FV0 = sqrtf((float)DO / (10.0f * (float)BEL * 9.0f));
  const float FV1 = sqrtf((float)DO / 360.0f);

  const float* dp = diff + (((size_t)n << 8) + (size_t)m) * 3;
  const float dx = dp[0], dy = dp[1], dz = dp[2];
  const float r2 = dx * dx + dy * dy + dz * dz;
  const float r  = sqrtf(r2);
  const float rr = fmaxf(r, 1e-8f);
  const float inv = 1.0f / rr;
  const float x = dx * inv, y = dy * inv, z = dz * inv;

  // Gaussian windows, pre-scaled by fv0 (folds layer-0 scale)
  float wv[4];
  {
    const float NORMC = 0.6649038006690546f;  // 1/(0.6*sqrt(2pi))
    const float RAD[4] = {0.5f, 1.0f, 1.5f, 2.0f};
#pragma unroll
    for (int k = 0; k < 4; ++k) {
      float tq = (r - RAD[k]) * (1.0f / 0.6f);
      wv[k] = expf(-0.5f * tq * tq) * (NORMC * FV0);
    }
  }

  // real spherical harmonics, replicating reference recurrences EXACTLY.
  float Y[25];
  {
    const float A1 = x,                 B1 = y * A1;
    const float A2 = x * A1 - y * B1,   B2 = x * B1 + y * A2;
    const float A3 = x * A2 - y * B2,   B3 = x * B2 + y * A3;
    const float A4 = x * A3 - y * B3,   B4 = x * B3 + y * A4;
    const float z2 = z * z;
    Y[0]  = 0.28209479177387814f;
    Y[1]  = 0.4886025119029199f * B1;
    Y[2]  = 0.4886025119029199f * z;
    Y[3]  = 0.4886025119029199f * A1;
    Y[4]  = 0.5462742152960396f * B2;
    Y[5]  = 1.0925484305920792f * z * B1;
    Y[6]  = 0.31539156525252005f * (3.0f * z2 - 1.0f);
    Y[7]  = 1.0925484305920792f * z * A1;
    Y[8]  = 0.5462742152960396f * A2;
    Y[9]  = 0.5900435899266435f * B3;
    Y[10] = 1.445305721320277f * z * B2;
    Y[11] = 0.4570457994644658f * (5.0f * z2 - 1.0f) * B1;
    Y[12] = 0.3731763325901154f * z * (5.0f * z2 - 3.0f);
    Y[13] = 0.4570457994644658f * (5.0f * z2 - 1.0f) * A1;
    Y[14] = 1.445305721320277f * z * A2;
    Y[15] = 0.5900435899266435f * A3;
    Y[16] = 0.6258357354491761f * B4;
    Y[17] = 1.7701307697799304f * z * B3;
    Y[18] = 0.47308734787878004f * (7.0f * z2 - 1.0f) * B2;
    Y[19] = 0.6690465435572892f * z * (7.0f * z2 - 3.0f) * B1;
    Y[20] = 0.10578554691520431f * ((35.0f * z2 - 30.0f) * z2 + 3.0f);
    Y[21] = 0.6690465435572892f * z * (7.0f * z2 - 3.0f) * A1;
    Y[22] = 0.47308734787878004f * (7.0f * z2 - 1.0f) * A2;
    Y[23] = 1.7701307697799304f * z * A3;
    Y[24] = 0.6258357354491761f * A4;
  }

  // collapse radial dim: c[t][j] = sum_r w0[t, r*NJ+j] * win_r * fv0
  float c[10][NJ];
#pragma unroll
  for (int t = 0; t < 10; ++t) {
#pragma unroll
    for (int j = 0; j < NJ; ++j) {
      float acc = 0.0f;
#pragma unroll
      for (int rx = 0; rx < 4; ++rx)
        acc = fmaf(w0g[W0OFF + t * BEL + rx * NJ + j], wv[rx], acc);
      c[t][j] = acc;
    }
  }
  float b0v[10];
#pragma unroll
  for (int t = 0; t < 10; ++t) b0v[t] = b0g[10 * P + t];

  // uniform base for this block's n-row; per-lane offset is just m
  float* __restrict__ outn = out + ((size_t)n << 8);
  const float* __restrict__ w1p = w1g + 160 * P;
  const float* __restrict__ b1p = b1g + 16 * P;

#pragma unroll 1
  for (int ai = 0; ai < NA; ++ai) {
    const int a = a0 + ai;
#pragma unroll
    for (int b = 0; b < DI; ++b) {
      // K[j] = sum_c Q[(a*DI+b), c] * Y_J[c]
      float K[NJ];
#pragma unroll
      for (int j = 0; j < NJ; ++j) {
        const int W = 2 * (JS + j) + 1;
        const int qbase = QOFF + qlocal(DO, DI, JS, j) + (a * DI + b) * W;
        float acc = 0.0f;
#pragma unroll
        for (int cc = 0; cc < 2 * (JS + j) + 1; ++cc)
          acc = fmaf(Q[qbase + cc], Y[YBASE[JS + j] + cc], acc);
        K[j] = acc;
      }
      // layer 0
      float h[10];
#pragma unroll
      for (int t = 0; t < 10; ++t) {
        float acc = b0v[t];
#pragma unroll
        for (int j = 0; j < NJ; ++j) acc = fmaf(c[t][j], K[j], acc);
        h[t] = fmaxf(acc, 0.0f);
      }
      // layer 1 + scatter (coalesced along m); plane pointer is wave-uniform
#pragma unroll
      for (int u = 0; u < 4; ++u) {
        const int Rr = ROFF + u * DO + a;
#pragma unroll
        for (int v = 0; v < 4; ++v) {
          const int uv = u * 4 + v;
          float acc = 0.0f;
#pragma unroll
          for (int t = 0; t < 10; ++t)
            acc = fmaf(w1p[uv * 10 + t], h[t], acc);
          const float val = fmaf(acc, FV1, b1p[uv]);
          const int Cc = COFF + v * DI + b;
          float* __restrict__ op = outn + (((size_t)(Rr * 36 + Cc)) << 16);
          op[m] = val;
        }
      }
    }
  }
}

// ============================================================================
// Light paths (0,1,2,3,6): one kernel, interleaved for balance
// ============================================================================
__global__ __launch_bounds__(256) void se3_light_kernel(
    const float* __restrict__ diff, const float* __restrict__ w0,
    const float* __restrict__ b0, const float* __restrict__ w1,
    const float* __restrict__ b1, const float* __restrict__ Q,
    float* __restrict__ out) {
  const int sel = blockIdx.x % 5;
  const int n   = blockIdx.x / 5;
  const int m   = threadIdx.x;
  switch (sel) {
    case 0: do_path<0,1>(diff, w0, b0, w1, b1, Q, out, 0, n, m); break;
    case 1: do_path<1,1>(diff, w0, b0, w1, b1, Q, out, 0, n, m); break;
    case 2: do_path<2,1>(diff, w0, b0, w1, b1, Q, out, 0, n, m); break;
    case 3: do_path<3,3>(diff, w0, b0, w1, b1, Q, out, 0, n, m); break;
    case 4: do_path<6,5>(diff, w0, b0, w1, b1, Q, out, 0, n, m); break;
  }
}

// ============================================================================
// Heavy paths: one kernel each, a-dimension split across blocks
// grid = DO * 256; block b: a0 = b % DO, n = b / DO
// ============================================================================
template <int P>
__global__ __launch_bounds__(256, 1) void se3_heavy_kernel(
    const float* __restrict__ diff, const float* __restrict__ w0,
    const float* __restrict__ b0, const float* __restrict__ w1,
    const float* __restrict__ b1, const float* __restrict__ Q,
    float* __restrict__ out) {
  constexpr int DO = 2 * (P / 3) + 1;
  const int a0 = blockIdx.x % DO;
  const int n  = blockIdx.x / DO;
  do_path<P, 1>(diff, w0, b0, w1, b1, Q, out, a0, n, threadIdx.x);
}

extern "C" void kernel_launch(void* const* d_in, const int* in_sizes, int n_in,
                              void* d_out, int out_size, void* d_ws, size_t ws_size,
                              hipStream_t stream) {
  const float* diff = (const float*)d_in[0];
  const float* w0   = (const float*)d_in[1];
  const float* b0   = (const float*)d_in[2];
  const float* w1   = (const float*)d_in[3];
  const float* b1   = (const float*)d_in[4];
  float* out = (float*)d_out;
  float* qws = (float*)d_ws;  // needs 1225 floats; rebuilt every call (ws is re-poisoned)

  init_q_kernel<<<dim3(19), dim3(256), 0, stream>>>(qws);
  // heavy first (largest write volume), then light
  se3_heavy_kernel<8><<<dim3(5 * 256), dim3(256), 0, stream>>>(diff, w0, b0, w1, b1, qws, out);
  se3_heavy_kernel<7><<<dim3(5 * 256), dim3(256), 0, stream>>>(diff, w0, b0, w1, b1, qws, out);
  se3_heavy_kernel<5><<<dim3(3 * 256), dim3(256), 0, stream>>>(diff, w0, b0, w1, b1, qws, out);
  se3_heavy_kernel<4><<<dim3(3 * 256), dim3(256), 0, stream>>>(diff, w0, b0, w1, b1, qws, out);
  se3_light_kernel<<<dim3(5 * 256), dim3(256), 0, stream>>>(diff, w0, b0, w1, b1, qws, out);
}